// Round 1
// baseline (416.280 us; speedup 1.0000x reference)
//
#include <hip/hip_runtime.h>
#include <hip/hip_bf16.h>

#define N_NODES 50000
#define N_EDGES 1600000
#define NBLK 196           // ceil(50000/256)
#define EBLK 6250          // ceil(1600000/256)
#define NGROUPS 12500      // ceil(50000/4), 4 nodes per wave-group

// ---------------- helpers ----------------
__device__ __forceinline__ int rlanei(int v, int l) {
  return __builtin_amdgcn_readlane(v, l);
}
__device__ __forceinline__ float rlanef(float v, int l) {
  return __int_as_float(__builtin_amdgcn_readlane(__float_as_int(v), l));
}

// ---------------- CSR build ----------------
__global__ void k_zero(int* deg) {
  int i = blockIdx.x * 256 + threadIdx.x;
  if (i < N_NODES) deg[i] = 0;
}

__global__ void k_count(const int* __restrict__ ei, int* __restrict__ deg) {
  int e = blockIdx.x * 256 + threadIdx.x;
  if (e < N_EDGES) atomicAdd(&deg[ei[N_EDGES + e]], 1);
}

__global__ void k_scan1(const int* __restrict__ deg, int* __restrict__ bsum) {
  __shared__ int sm[256];
  int t = threadIdx.x;
  int i = blockIdx.x * 256 + t;
  sm[t] = (i < N_NODES) ? deg[i] : 0;
  __syncthreads();
  for (int off = 128; off > 0; off >>= 1) {
    if (t < off) sm[t] += sm[t + off];
    __syncthreads();
  }
  if (t == 0) bsum[blockIdx.x] = sm[0];
}

__global__ void k_scan2(const int* __restrict__ bsum, int* __restrict__ boff) {
  __shared__ int sm[256];
  int t = threadIdx.x;
  int v = (t < NBLK) ? bsum[t] : 0;
  sm[t] = v;
  __syncthreads();
  for (int off = 1; off < 256; off <<= 1) {
    int u = (t >= off) ? sm[t - off] : 0;
    __syncthreads();
    sm[t] += u;
    __syncthreads();
  }
  if (t < NBLK) boff[t] = sm[t] - v;  // exclusive
}

__global__ void k_scan3(const int* __restrict__ deg, const int* __restrict__ boff,
                        int* __restrict__ rowptr, int* __restrict__ cursor,
                        float* __restrict__ dinv) {
  __shared__ int sm[256];
  int t = threadIdx.x;
  int i = blockIdx.x * 256 + t;
  int v = (i < N_NODES) ? deg[i] : 0;
  sm[t] = v;
  __syncthreads();
  for (int off = 1; off < 256; off <<= 1) {
    int u = (t >= off) ? sm[t - off] : 0;
    __syncthreads();
    sm[t] += u;
    __syncthreads();
  }
  int rp = boff[blockIdx.x] + sm[t] - v;  // exclusive prefix
  if (i < N_NODES) {
    rowptr[i] = rp;
    cursor[i] = rp;
    dinv[i] = rsqrtf((float)v + 2.0f);
  }
  if (i == 0) rowptr[N_NODES] = N_EDGES;
}

__global__ void k_scatter(const int* __restrict__ ei, int* __restrict__ cursor,
                          int* __restrict__ srcs) {
  int e = blockIdx.x * 256 + threadIdx.x;
  if (e < N_EDGES) {
    int d = ei[N_EDGES + e];
    int p = atomicAdd(&cursor[d], 1);
    srcs[p] = ei[e];
  }
}

// ---------------- weight composition ----------------
// Mz = W_z @ Wl_z[:64]; Mh = W_h @ Wl_h[:64] (interleaved float2)
// bz' = b_z @ Wl_z[:64] + bl_z; bh' likewise.
__global__ void k_compose(const float* __restrict__ Wz, const float* __restrict__ bz,
                          const float* __restrict__ Wlz, const float* __restrict__ blz,
                          const float* __restrict__ Wh, const float* __restrict__ bh,
                          const float* __restrict__ Wlh, const float* __restrict__ blh,
                          float2* __restrict__ M, float2* __restrict__ B2) {
  int t = blockIdx.x * 256 + threadIdx.x;
  if (t < 4096) {
    int i = t >> 6, c = t & 63;
    float mz = 0.f, mh = 0.f;
    for (int j = 0; j < 64; ++j) {
      mz = fmaf(Wz[i * 64 + j], Wlz[j * 64 + c], mz);
      mh = fmaf(Wh[i * 64 + j], Wlh[j * 64 + c], mh);
    }
    M[t] = make_float2(mz, mh);
  } else if (t < 4160) {
    int c = t - 4096;
    float vz = blz[c], vh = blh[c];
    for (int j = 0; j < 64; ++j) {
      vz = fmaf(bz[j], Wlz[j * 64 + c], vz);
      vh = fmaf(bh[j], Wlh[j * 64 + c], vh);
    }
    B2[c] = make_float2(vz, vh);
  }
}

// ---------------- fused aggregate + cell + readout ----------------
// wave = 4 consecutive nodes; lane = channel (0..63).
// sx[v] = dinv[v] * (sum_{e into v} dinv[src]*x[src] + 2*dinv[v]*x[v])
// Z = sigmoid(sx.Mz + bz'), Ht = tanh(sx.Mh + bh'), h = relu((1-Z)*Ht)
// out[v] = h . W_out + b_out   (45 cols)
__global__ __launch_bounds__(256, 3) void k_agg(
    const float* __restrict__ x, const int* __restrict__ rowptr,
    const int* __restrict__ srcs, const float* __restrict__ dinv,
    const float2* __restrict__ M, const float2* __restrict__ B2,
    const float* __restrict__ Wout, const float* __restrict__ bout,
    float* __restrict__ out) {
  __shared__ float2 sM[4096];   // 32 KB  (Mz,Mh interleaved, [k*64+c])
  __shared__ float sW[2880];    // 11.25 KB (W_out [k*45+c])
  __shared__ float2 sB[64];     // fused biases
  __shared__ float sbo[48];
  int tid = threadIdx.x;
  for (int i = tid; i < 4096; i += 256) sM[i] = M[i];
  for (int i = tid; i < 2880; i += 256) sW[i] = Wout[i];
  if (tid < 64) sB[tid] = B2[tid];
  if (tid < 45) sbo[tid] = bout[tid];
  __syncthreads();

  int lane = tid & 63;
  int wave = blockIdx.x * 4 + (tid >> 6);
  int nwaves = gridDim.x * 4;

  for (int g = wave; g < NGROUPS; g += nwaves) {
    int v0 = g * 4;
    float sx[4];
    // ---- gather phase ----
    #pragma unroll
    for (int n = 0; n < 4; ++n) {
      int v = v0 + n;
      float a0 = 0.f, a1 = 0.f;
      if (v < N_NODES) {
        int r0 = rowptr[v], r1 = rowptr[v + 1];
        for (int e = r0; e < r1; e += 64) {
          int sv = (e + lane < r1) ? srcs[e + lane] : 0;
          int m = min(64, r1 - e);
          int j = 0;
          for (; j + 7 < m; j += 8) {
            int s0 = rlanei(sv, j),     s1 = rlanei(sv, j + 1);
            int s2 = rlanei(sv, j + 2), s3 = rlanei(sv, j + 3);
            int s4 = rlanei(sv, j + 4), s5 = rlanei(sv, j + 5);
            int s6 = rlanei(sv, j + 6), s7 = rlanei(sv, j + 7);
            a0 = fmaf(dinv[s0], x[s0 * 64 + lane], a0);
            a1 = fmaf(dinv[s1], x[s1 * 64 + lane], a1);
            a0 = fmaf(dinv[s2], x[s2 * 64 + lane], a0);
            a1 = fmaf(dinv[s3], x[s3 * 64 + lane], a1);
            a0 = fmaf(dinv[s4], x[s4 * 64 + lane], a0);
            a1 = fmaf(dinv[s5], x[s5 * 64 + lane], a1);
            a0 = fmaf(dinv[s6], x[s6 * 64 + lane], a0);
            a1 = fmaf(dinv[s7], x[s7 * 64 + lane], a1);
          }
          for (; j < m; ++j) {
            int s = rlanei(sv, j);
            a0 = fmaf(dinv[s], x[s * 64 + lane], a0);
          }
        }
        float dv = dinv[v];
        float xv = x[v * 64 + lane];
        sx[n] = dv * ((a0 + a1) + 2.f * dv * xv);
      } else {
        sx[n] = 0.f;
      }
    }
    // ---- fused cell matvecs: z = sx.Mz, h = sx.Mh ----
    float z[4], h[4];
    #pragma unroll
    for (int n = 0; n < 4; ++n) { z[n] = sB[lane].x; h[n] = sB[lane].y; }
    #pragma unroll 8
    for (int k = 0; k < 64; ++k) {
      float2 wv = sM[k * 64 + lane];
      #pragma unroll
      for (int n = 0; n < 4; ++n) {
        float sk = rlanef(sx[n], k);
        z[n] = fmaf(sk, wv.x, z[n]);
        h[n] = fmaf(sk, wv.y, h[n]);
      }
    }
    // ---- nonlinearity + gate (H=0 => H_new = (1-Z)*tanh(h)) ----
    #pragma unroll
    for (int n = 0; n < 4; ++n) {
      float Z = 1.f / (1.f + __expf(-z[n]));
      float t = fminf(15.f, fmaxf(-15.f, h[n]));
      float e2 = __expf(-2.f * t);
      float Th = (1.f - e2) / (1.f + e2);
      sx[n] = fmaxf((1.f - Z) * Th, 0.f);   // relu(H)
    }
    // ---- readout: out = relu(H) @ W_out + b_out ----
    float o[4] = {0.f, 0.f, 0.f, 0.f};
    #pragma unroll 8
    for (int k = 0; k < 64; ++k) {
      float wv = (lane < 45) ? sW[k * 45 + lane] : 0.f;
      #pragma unroll
      for (int n = 0; n < 4; ++n) {
        float hk = rlanef(sx[n], k);
        o[n] = fmaf(hk, wv, o[n]);
      }
    }
    if (lane < 45) {
      #pragma unroll
      for (int n = 0; n < 4; ++n) {
        int v = v0 + n;
        if (v < N_NODES) out[v * 45 + lane] = o[n] + sbo[lane];
      }
    }
  }
}

// ---------------- launch ----------------
extern "C" void kernel_launch(void* const* d_in, const int* in_sizes, int n_in,
                              void* d_out, int out_size, void* d_ws, size_t ws_size,
                              hipStream_t stream) {
  const float* x    = (const float*)d_in[0];
  const int*   ei   = (const int*)d_in[1];
  const float* Wz   = (const float*)d_in[2];
  const float* bz   = (const float*)d_in[3];
  const float* Wlz  = (const float*)d_in[4];
  const float* blz  = (const float*)d_in[5];
  // d_in[6..9] (W_r branch) are dead: H=0 => H*R=0.
  const float* Wh   = (const float*)d_in[10];
  const float* bh   = (const float*)d_in[11];
  const float* Wlh  = (const float*)d_in[12];
  const float* blh  = (const float*)d_in[13];
  const float* Wout = (const float*)d_in[14];
  const float* bout = (const float*)d_in[15];
  float* out = (float*)d_out;

  char* w = (char*)d_ws;
  int*    deg    = (int*)(w + 0);          // 50000 ints
  int*    rowptr = (int*)(w + 200192);     // 50001 ints
  int*    cursor = (int*)(w + 400384);     // 50000 ints
  int*    bsum   = (int*)(w + 600576);     // 196 ints
  int*    boff   = (int*)(w + 601600);     // 196 ints
  int*    srcs   = (int*)(w + 602624);     // 1.6M ints
  float*  dinvp  = (float*)(w + 7002624);  // 50000 floats
  float2* M      = (float2*)(w + 7202816); // 4096 float2
  float2* B2     = (float2*)(w + 7235584); // 64 float2
  // total ~7.24 MB of ws

  k_zero<<<NBLK, 256, 0, stream>>>(deg);
  k_count<<<EBLK, 256, 0, stream>>>(ei, deg);
  k_scan1<<<NBLK, 256, 0, stream>>>(deg, bsum);
  k_scan2<<<1, 256, 0, stream>>>(bsum, boff);
  k_scan3<<<NBLK, 256, 0, stream>>>(deg, boff, rowptr, cursor, dinvp);
  k_scatter<<<EBLK, 256, 0, stream>>>(ei, cursor, srcs);
  k_compose<<<17, 256, 0, stream>>>(Wz, bz, Wlz, blz, Wh, bh, Wlh, blh, M, B2);
  k_agg<<<768, 256, 0, stream>>>(x, rowptr, srcs, dinvp, M, B2, Wout, bout, out);
}